// Round 5
// baseline (415.074 us; speedup 1.0000x reference)
//
#include <hip/hip_runtime.h>
#include <hip/hip_cooperative_groups.h>
#include <math.h>

namespace cg = cooperative_groups;

#define Bq 8
#define T 512
#define D 1024
#define R 4
#define V 2048
#define NCOL (V * R * R)        // 32768 columns of w_vocab
#define DSPLIT 16
#define DCHUNK (D / DSPLIT)     // 64 d-rows per core-phase block
#define CBLK 1024               // cols per core-phase block (256 thr * float4)
#define NBLK 512                // cooperative grid: 2 blocks/CU co-resident

// ---------------------------------------------------------------------------
// Single cooperative kernel, 512 blocks x 256 threads, phases split by
// grid.sync(). Removes 3 dispatch gaps + per-kernel BW ramp/drain + the
// partial-buffer round trip of the 4-kernel version.
//  A: x-reduce -> xbar (atomicAdd into pre-zeroed xbar; 256 active blocks)
//  B: core: part[ds][b][col] = sum_{d in chunk} xbar[b][d]*wv[d][col]
//     (512 blocks stream the full 128 MiB of wv exactly once)
//  C: gather+normalize -> Mn (64 active blocks)
//  D: per-batch TT chain + loss (8 active blocks)
// ---------------------------------------------------------------------------
__global__ __launch_bounds__(256, 2) void k_mega(
    const float* __restrict__ x, const int* __restrict__ labels,
    const float* __restrict__ wa, const float* __restrict__ wb,
    const float* __restrict__ wv, float* __restrict__ out,
    float* __restrict__ xbar, float* __restrict__ part, float* __restrict__ Mn) {

    cg::grid_group grid = cg::this_grid();
    __shared__ float xs[Bq * DCHUNK];   // 2 KB   (phase B)
    __shared__ float mats[64][17];      // 4.25 KB (phase D, +1 pad)
    __shared__ float abp[64];
    int blk = blockIdx.x;
    int tid = threadIdx.x;              // 0..255

    // ---- phase A: x reduce -> xbar (xbar pre-zeroed by memsetAsync) ----
    if (blk == 0 && tid == 0) out[0] = 0.f;
    if (blk < 256) {
        int b  = blk >> 5;              // 0..7
        int tc = blk & 31;              // 32 chunks of 16 timesteps
        const float4* xp = (const float4*)(x + ((size_t)b * T + (size_t)tc * 16) * D) + tid;
        float4 acc = make_float4(0.f, 0.f, 0.f, 0.f);
#pragma unroll
        for (int t = 0; t < 16; ++t) {
            float4 v = xp[t * (D / 4)];
            acc.x += v.x; acc.y += v.y; acc.z += v.z; acc.w += v.w;
        }
        float* dst = xbar + b * D + tid * 4;
        atomicAdd(dst + 0, acc.x);
        atomicAdd(dst + 1, acc.y);
        atomicAdd(dst + 2, acc.z);
        atomicAdd(dst + 3, acc.w);
    }
    grid.sync();

    // ---- phase B: core (all 512 blocks) ----
    {
        int colb = blk >> 4;            // 0..31
        int ds   = blk & 15;            // 0..15
        int d0   = ds * DCHUNK;

        if (tid < 128) {                // 512 floats of xbar slice -> LDS
            int q4 = tid * 4;
            int b  = q4 >> 6;
            int dd = q4 & 63;
            *(float4*)(xs + q4) = *(const float4*)(xbar + b * D + d0 + dd);
        }
        __syncthreads();

        int col = colb * CBLK + tid * 4;
        const float4* wp = (const float4*)(wv + (size_t)d0 * NCOL + col);
        float4 acc[Bq];
#pragma unroll
        for (int b = 0; b < Bq; ++b) acc[b] = make_float4(0.f, 0.f, 0.f, 0.f);

#pragma unroll 8
        for (int d = 0; d < DCHUNK; ++d) {
            float4 w = wp[(size_t)d * (NCOL / 4)];
#pragma unroll
            for (int b = 0; b < Bq; ++b) {
                float xv = xs[b * DCHUNK + d];
                acc[b].x += w.x * xv;
                acc[b].y += w.y * xv;
                acc[b].z += w.z * xv;
                acc[b].w += w.w * xv;
            }
        }

#pragma unroll
        for (int b = 0; b < Bq; ++b)
            *(float4*)(part + ((size_t)ds * Bq + b) * NCOL + col) = acc[b];
    }
    grid.sync();

    // ---- phase C: gather + column-normalize -> Mn (64 active blocks) ----
    if (blk < 64) {
        int b  = blk >> 3;
        int tc = blk & 7;
        int tl = tid >> 2;              // 0..63
        int i  = tid & 3;               // matrix row
        int t  = tc * 64 + tl;
        int y  = labels[b * T + t];

        const float* pb = part + (size_t)b * NCOL + (size_t)i * (V * R) + (size_t)y * R;
        float4 g = make_float4(0.f, 0.f, 0.f, 0.f);
#pragma unroll
        for (int ds = 0; ds < DSPLIT; ++ds) {
            float4 v = *(const float4*)(pb + (size_t)ds * (Bq * NCOL));
            g.x += v.x; g.y += v.y; g.z += v.z; g.w += v.w;
        }
        g.x = fabsf(g.x); g.y = fabsf(g.y); g.z = fabsf(g.z); g.w = fabsf(g.w);

        float sx = g.x, sy = g.y, sz = g.z, sw = g.w;
        sx += __shfl_xor(sx, 1); sy += __shfl_xor(sy, 1);
        sz += __shfl_xor(sz, 1); sw += __shfl_xor(sw, 1);
        sx += __shfl_xor(sx, 2); sy += __shfl_xor(sy, 2);
        sz += __shfl_xor(sz, 2); sw += __shfl_xor(sw, 2);

        float4 o = make_float4(g.x / sx, g.y / sy, g.z / sz, g.w / sw);
        *(float4*)(Mn + ((size_t)(b * T + t)) * 16 + i * 4) = o;
    }
    grid.sync();

    // ---- phase D: per-batch chain + loss (8 active blocks) ----
    if (blk < Bq) {
        int b = blk;
        // alpha/beta partial dots: threads 0..63
        if (tid < 64) {
            int r   = tid & 3;
            int sel = (tid >> 2) & 1;
            int seg = tid >> 3;         // 0..7, 128 d each
            const float* w  = sel ? wb : wa;
            const float* xp = xbar + b * D;
            float s = 0.f;
#pragma unroll 8
            for (int d = seg * 128; d < seg * 128 + 128; ++d)
                s += xp[d] * w[d * R + r];
            abp[tid] = s;
        }

        // chunk product P = M_{c*8+7} ... M_{c*8}, c = tid in [0,64)
        int c = tid;
        if (c < 64) {
            const float* mp = Mn + ((size_t)b * T + (size_t)c * 8) * 16;
            float P[R][R];
            {
                float4 m0 = *(const float4*)(mp + 0);
                float4 m1 = *(const float4*)(mp + 4);
                float4 m2 = *(const float4*)(mp + 8);
                float4 m3 = *(const float4*)(mp + 12);
                P[0][0]=m0.x; P[0][1]=m0.y; P[0][2]=m0.z; P[0][3]=m0.w;
                P[1][0]=m1.x; P[1][1]=m1.y; P[1][2]=m1.z; P[1][3]=m1.w;
                P[2][0]=m2.x; P[2][1]=m2.y; P[2][2]=m2.z; P[2][3]=m2.w;
                P[3][0]=m3.x; P[3][1]=m3.y; P[3][2]=m3.z; P[3][3]=m3.w;
            }
#pragma unroll
            for (int t = 1; t < 8; ++t) {
                float4 m0 = *(const float4*)(mp + t * 16 + 0);
                float4 m1 = *(const float4*)(mp + t * 16 + 4);
                float4 m2 = *(const float4*)(mp + t * 16 + 8);
                float4 m3 = *(const float4*)(mp + t * 16 + 12);
                float M[R][R] = {{m0.x, m0.y, m0.z, m0.w},
                                 {m1.x, m1.y, m1.z, m1.w},
                                 {m2.x, m2.y, m2.z, m2.w},
                                 {m3.x, m3.y, m3.z, m3.w}};
                float N[R][R];
#pragma unroll
                for (int i = 0; i < R; ++i)
#pragma unroll
                    for (int j = 0; j < R; ++j)
                        N[i][j] = M[i][0] * P[0][j] + M[i][1] * P[1][j] +
                                  M[i][2] * P[2][j] + M[i][3] * P[3][j];
#pragma unroll
                for (int i = 0; i < R; ++i)
#pragma unroll
                    for (int j = 0; j < R; ++j) P[i][j] = N[i][j];
            }
#pragma unroll
            for (int i = 0; i < R; ++i)
#pragma unroll
                for (int j = 0; j < R; ++j) mats[c][i * 4 + j] = P[i][j];
        }
        __syncthreads();

        // in-order tree combine: C_c <- C_{c+step} * C_c
        for (int rnd = 0; rnd < 6; ++rnd) {
            int step = 1 << rnd;
            bool act = (c < 64) && ((c & (2 * step - 1)) == 0);
            float N2[R][R];
            if (act) {
                float A[R][R], Bm[R][R];
#pragma unroll
                for (int i = 0; i < R; ++i)
#pragma unroll
                    for (int j = 0; j < R; ++j) {
                        A[i][j]  = mats[c + step][i * 4 + j];
                        Bm[i][j] = mats[c][i * 4 + j];
                    }
#pragma unroll
                for (int i = 0; i < R; ++i)
#pragma unroll
                    for (int j = 0; j < R; ++j)
                        N2[i][j] = A[i][0] * Bm[0][j] + A[i][1] * Bm[1][j] +
                                   A[i][2] * Bm[2][j] + A[i][3] * Bm[3][j];
            }
            __syncthreads();
            if (act) {
#pragma unroll
                for (int i = 0; i < R; ++i)
#pragma unroll
                    for (int j = 0; j < R; ++j) mats[c][i * 4 + j] = N2[i][j];
            }
            __syncthreads();
        }

        if (tid == 0) {
            float a[R], be[R];
#pragma unroll
            for (int r = 0; r < R; ++r) {
                float sa = 0.f, sb = 0.f;
#pragma unroll
                for (int seg = 0; seg < 8; ++seg) {
                    sa += abp[(seg << 3) | r];
                    sb += abp[(seg << 3) | 4 | r];
                }
                a[r] = sa; be[r] = sb;
            }
            float sa = fabsf(a[0]) + fabsf(a[1]) + fabsf(a[2]) + fabsf(a[3]);
            float v0[R];
#pragma unroll
            for (int r = 0; r < R; ++r) v0[r] = fabsf(a[r]) / sa;
            float v[R];
#pragma unroll
            for (int i = 0; i < R; ++i)
                v[i] = mats[0][i * 4 + 0] * v0[0] + mats[0][i * 4 + 1] * v0[1] +
                       mats[0][i * 4 + 2] * v0[2] + mats[0][i * 4 + 3] * v0[3];
            float sb = fabsf(be[0]) + fabsf(be[1]) + fabsf(be[2]) + fabsf(be[3]);
            float prob = (fabsf(be[0]) * v[0] + fabsf(be[1]) * v[1] +
                          fabsf(be[2]) * v[2] + fabsf(be[3]) * v[3]) / sb;
            atomicAdd(out, -logf(prob) * 0.125f);
        }
    }
}

extern "C" void kernel_launch(void* const* d_in, const int* in_sizes, int n_in,
                              void* d_out, int out_size, void* d_ws, size_t ws_size,
                              hipStream_t stream) {
    const float* x      = (const float*)d_in[0];   // [8,512,1024] fp32
    const int*   labels = (const int*)d_in[1];     // [8,512] int32
    const float* wa     = (const float*)d_in[2];   // [1024,4]
    const float* wb     = (const float*)d_in[3];   // [1024,4]
    const float* wv     = (const float*)d_in[4];   // [1024,32768]
    float* out = (float*)d_out;                    // scalar loss

    float* xbar = (float*)d_ws;                              // 8192 floats
    float* part = xbar + Bq * D;                             // 16*8*32768 = 16 MiB
    float* Mn   = part + (size_t)DSPLIT * Bq * NCOL;         // 65536 floats

    hipMemsetAsync(xbar, 0, Bq * D * sizeof(float), stream);

    void* args[] = {(void*)&x, (void*)&labels, (void*)&wa, (void*)&wb,
                    (void*)&wv, (void*)&out, (void*)&xbar, (void*)&part, (void*)&Mn};
    hipLaunchCooperativeKernel((const void*)k_mega, dim3(NBLK), dim3(256),
                               args, 0, stream);
}

// Round 6
// 252.557 us; speedup vs baseline: 1.6435x; 1.6435x over previous
//
#include <hip/hip_runtime.h>
#include <math.h>

#define Bq 8
#define T 512
#define D 1024
#define R 4
#define V 2048
#define NCOL (V * R * R)        // 32768 columns of w_vocab
#define DSPLIT 16
#define DCHUNK (D / DSPLIT)     // 64 d-rows per k_core block
#define CBLK 1024               // cols per k_core block (256 thr * float4)
#define NTC 32                  // t-chunks in k_xbar (16 t each)

// ---------------------------------------------------------------------------
// K1: partial[b][tc][d] = sum of 16 t's of x[b][.][d].  No atomics, no memset.
// grid (8, 32) x 256 threads, float4 coalesced loads+stores.
// Block (0,0) thread 0 zeroes the output scalar (replaces a memset).
// ---------------------------------------------------------------------------
__global__ void k_xbar(const float* __restrict__ x, float* __restrict__ partial,
                       float* __restrict__ out) {
    int b   = blockIdx.x;
    int tc  = blockIdx.y;          // 32 chunks of 16 timesteps
    int tid = threadIdx.x;         // 256 -> 1024 d via float4
    if (b == 0 && tc == 0 && tid == 0) out[0] = 0.f;
    const float4* xp = (const float4*)(x + ((size_t)b * T + (size_t)tc * 16) * D) + tid;
    float4 acc = make_float4(0.f, 0.f, 0.f, 0.f);
#pragma unroll
    for (int t = 0; t < 16; ++t) {
        float4 v = xp[t * (D / 4)];
        acc.x += v.x; acc.y += v.y; acc.z += v.z; acc.w += v.w;
    }
    *(float4*)(partial + ((size_t)b * NTC + tc) * D + tid * 4) = acc;
}

// ---------------------------------------------------------------------------
// K2: part[ds][b][col] = sum_{d in chunk ds} xbar[b][d] * w_vocab[d][col]
// grid (32, 16) x 256 threads. Prologue reduces partial[b][tc][d-slice] ->
// xs in LDS (L2-resident reads, shared by 32 colb-blocks).
// colb==0 blocks also write xbar back to global for the chain's alpha/beta.
// Main loop streams the full 128 MB of w_vocab exactly once (8 waves/CU,
// unroll 8 -> 8 KB/wave in flight).
// ---------------------------------------------------------------------------
__global__ void k_core(const float* __restrict__ wv, const float* __restrict__ partial,
                       float* __restrict__ xbar, float* __restrict__ part) {
    __shared__ float xs[Bq * DCHUNK];  // 8 x 64 floats = 2 KB
    int tid  = threadIdx.x;            // 0..255
    int colb = blockIdx.x;             // 0..31
    int ds   = blockIdx.y;             // 0..15
    int d0   = ds * DCHUNK;

    // reduce partial -> xs (512 values, 2 per thread)
#pragma unroll
    for (int h = 0; h < 2; ++h) {
        int q  = tid + h * 256;        // 0..511
        int b  = q >> 6;
        int dd = q & 63;
        const float* pp = partial + (size_t)b * NTC * D + d0 + dd;
        float s = 0.f;
#pragma unroll
        for (int tc = 0; tc < NTC; ++tc) s += pp[(size_t)tc * D];
        xs[q] = s;
    }
    __syncthreads();

    if (colb == 0 && tid < 128) {      // write xbar slice back for the chain
        int q4 = tid * 4;
        int b  = q4 >> 6;
        int dd = q4 & 63;
        *(float4*)(xbar + b * D + d0 + dd) = *(const float4*)(xs + q4);
    }

    int col = colb * CBLK + tid * 4;
    const float4* wp = (const float4*)(wv + (size_t)d0 * NCOL + col);
    float4 acc[Bq];
#pragma unroll
    for (int b = 0; b < Bq; ++b) acc[b] = make_float4(0.f, 0.f, 0.f, 0.f);

#pragma unroll 8
    for (int d = 0; d < DCHUNK; ++d) {
        float4 w = wp[(size_t)d * (NCOL / 4)];
#pragma unroll
        for (int b = 0; b < Bq; ++b) {
            float xv = xs[b * DCHUNK + d];
            acc[b].x += w.x * xv;
            acc[b].y += w.y * xv;
            acc[b].z += w.z * xv;
            acc[b].w += w.w * xv;
        }
    }

#pragma unroll
    for (int b = 0; b < Bq; ++b)
        *(float4*)(part + ((size_t)ds * Bq + b) * NCOL + col) = acc[b];
}

// ---------------------------------------------------------------------------
// K3 (fused gather + chain): one block per batch, 1024 threads (16 waves) —
// keeps the gather's memory-level parallelism (4096 in-flight load chains of
// 16) while the chain phase reads Mn from LDS. Saves one dispatch gap + the
// Mn global round-trip vs the 4-kernel version.
// ---------------------------------------------------------------------------
__global__ __launch_bounds__(1024) void k_fuse(
    const float* __restrict__ part, const int* __restrict__ labels,
    const float* __restrict__ xbar, const float* __restrict__ wa,
    const float* __restrict__ wb, float* __restrict__ out) {
    __shared__ float Mn_s[T * 16];    // 32 KB
    __shared__ float mats[64][17];    // +1 pad
    __shared__ float abp[64];
    int b   = blockIdx.x;
    int tid = threadIdx.x;            // 0..1023

    // ---- alpha/beta partial dots (threads 0..63) ----
    if (tid < 64) {
        int r   = tid & 3;
        int sel = (tid >> 2) & 1;
        int seg = tid >> 3;           // 0..7, 128 d each
        const float* w  = sel ? wb : wa;
        const float* xp = xbar + b * D;
        float s = 0.f;
#pragma unroll 8
        for (int d = seg * 128; d < seg * 128 + 128; ++d)
            s += xp[d] * w[d * R + r];
        abp[tid] = s;
    }

    // ---- gather + column-normalize into LDS: thread = (t, i), 2 halves ----
    {
        int tb = tid >> 2;            // 0..255
        int i  = tid & 3;             // matrix row
#pragma unroll
        for (int half = 0; half < 2; ++half) {
            int t = tb + half * 256;
            int y = labels[b * T + t];
            const float* pb = part + (size_t)b * NCOL + (size_t)i * (V * R) + (size_t)y * R;
            float4 g = make_float4(0.f, 0.f, 0.f, 0.f);
#pragma unroll
            for (int ds = 0; ds < DSPLIT; ++ds) {
                float4 v = *(const float4*)(pb + (size_t)ds * (Bq * NCOL));
                g.x += v.x; g.y += v.y; g.z += v.z; g.w += v.w;
            }
            g.x = fabsf(g.x); g.y = fabsf(g.y); g.z = fabsf(g.z); g.w = fabsf(g.w);

            // all-reduce over the 4-lane i-group
            float sx = g.x, sy = g.y, sz = g.z, sw = g.w;
            sx += __shfl_xor(sx, 1); sy += __shfl_xor(sy, 1);
            sz += __shfl_xor(sz, 1); sw += __shfl_xor(sw, 1);
            sx += __shfl_xor(sx, 2); sy += __shfl_xor(sy, 2);
            sz += __shfl_xor(sz, 2); sw += __shfl_xor(sw, 2);

            float4 o = make_float4(g.x / sx, g.y / sy, g.z / sz, g.w / sw);
            *(float4*)(Mn_s + t * 16 + i * 4) = o;
        }
    }
    __syncthreads();

    // ---- chunk product P = M_{c*8+7} ... M_{c*8} (threads 0..63) ----
    int c = tid;
    if (c < 64) {
        const float* mp = Mn_s + c * 8 * 16;
        float P[R][R];
        {
            float4 m0 = *(const float4*)(mp + 0);
            float4 m1 = *(const float4*)(mp + 4);
            float4 m2 = *(const float4*)(mp + 8);
            float4 m3 = *(const float4*)(mp + 12);
            P[0][0]=m0.x; P[0][1]=m0.y; P[0][2]=m0.z; P[0][3]=m0.w;
            P[1][0]=m1.x; P[1][1]=m1.y; P[1][2]=m1.z; P[1][3]=m1.w;
            P[2][0]=m2.x; P[2][1]=m2.y; P[2][2]=m2.z; P[2][3]=m2.w;
            P[3][0]=m3.x; P[3][1]=m3.y; P[3][2]=m3.z; P[3][3]=m3.w;
        }
#pragma unroll
        for (int t = 1; t < 8; ++t) {
            float4 m0 = *(const float4*)(mp + t * 16 + 0);
            float4 m1 = *(const float4*)(mp + t * 16 + 4);
            float4 m2 = *(const float4*)(mp + t * 16 + 8);
            float4 m3 = *(const float4*)(mp + t * 16 + 12);
            float M[R][R] = {{m0.x, m0.y, m0.z, m0.w},
                             {m1.x, m1.y, m1.z, m1.w},
                             {m2.x, m2.y, m2.z, m2.w},
                             {m3.x, m3.y, m3.z, m3.w}};
            float N[R][R];
#pragma unroll
            for (int i = 0; i < R; ++i)
#pragma unroll
                for (int j = 0; j < R; ++j)
                    N[i][j] = M[i][0] * P[0][j] + M[i][1] * P[1][j] +
                              M[i][2] * P[2][j] + M[i][3] * P[3][j];
#pragma unroll
            for (int i = 0; i < R; ++i)
#pragma unroll
                for (int j = 0; j < R; ++j) P[i][j] = N[i][j];
        }
#pragma unroll
        for (int i = 0; i < R; ++i)
#pragma unroll
            for (int j = 0; j < R; ++j) mats[c][i * 4 + j] = P[i][j];
    }
    __syncthreads();

    // ---- in-order tree combine: C_c <- C_{c+step} * C_c ----
    for (int rnd = 0; rnd < 6; ++rnd) {
        int step = 1 << rnd;
        bool act = (c < 64) && ((c & (2 * step - 1)) == 0);
        float N2[R][R];
        if (act) {
            float A[R][R], Bm[R][R];
#pragma unroll
            for (int i = 0; i < R; ++i)
#pragma unroll
                for (int j = 0; j < R; ++j) {
                    A[i][j]  = mats[c + step][i * 4 + j];
                    Bm[i][j] = mats[c][i * 4 + j];
                }
#pragma unroll
            for (int i = 0; i < R; ++i)
#pragma unroll
                for (int j = 0; j < R; ++j)
                    N2[i][j] = A[i][0] * Bm[0][j] + A[i][1] * Bm[1][j] +
                               A[i][2] * Bm[2][j] + A[i][3] * Bm[3][j];
        }
        __syncthreads();
        if (act) {
#pragma unroll
            for (int i = 0; i < R; ++i)
#pragma unroll
                for (int j = 0; j < R; ++j) mats[c][i * 4 + j] = N2[i][j];
        }
        __syncthreads();
    }

    // ---- finalize this batch ----
    if (tid == 0) {
        float a[R], be[R];
#pragma unroll
        for (int r = 0; r < R; ++r) {
            float sa = 0.f, sb = 0.f;
#pragma unroll
            for (int seg = 0; seg < 8; ++seg) {
                sa += abp[(seg << 3) | r];
                sb += abp[(seg << 3) | 4 | r];
            }
            a[r] = sa; be[r] = sb;
        }
        float sa = fabsf(a[0]) + fabsf(a[1]) + fabsf(a[2]) + fabsf(a[3]);
        float v0[R];
#pragma unroll
        for (int r = 0; r < R; ++r) v0[r] = fabsf(a[r]) / sa;
        float v[R];
#pragma unroll
        for (int i = 0; i < R; ++i)
            v[i] = mats[0][i * 4 + 0] * v0[0] + mats[0][i * 4 + 1] * v0[1] +
                   mats[0][i * 4 + 2] * v0[2] + mats[0][i * 4 + 3] * v0[3];
        float sb = fabsf(be[0]) + fabsf(be[1]) + fabsf(be[2]) + fabsf(be[3]);
        float prob = (fabsf(be[0]) * v[0] + fabsf(be[1]) * v[1] +
                      fabsf(be[2]) * v[2] + fabsf(be[3]) * v[3]) / sb;
        atomicAdd(out, -logf(prob) * 0.125f);
    }
}

extern "C" void kernel_launch(void* const* d_in, const int* in_sizes, int n_in,
                              void* d_out, int out_size, void* d_ws, size_t ws_size,
                              hipStream_t stream) {
    const float* x      = (const float*)d_in[0];   // [8,512,1024] fp32
    const int*   labels = (const int*)d_in[1];     // [8,512] int32
    const float* wa     = (const float*)d_in[2];   // [1024,4]
    const float* wb     = (const float*)d_in[3];   // [1024,4]
    const float* wv     = (const float*)d_in[4];   // [1024,32768]
    float* out = (float*)d_out;                    // scalar loss

    float* xbar    = (float*)d_ws;                           // 8192 floats
    float* partial = xbar + Bq * D;                          // 8*32*1024 = 1 MiB
    float* part    = partial + (size_t)Bq * NTC * D;         // 16*8*32768 = 16 MiB

    k_xbar<<<dim3(Bq, NTC), 256, 0, stream>>>(x, partial, out);
    k_core<<<dim3(NCOL / CBLK, DSPLIT), 256, 0, stream>>>(wv, partial, xbar, part);
    k_fuse<<<Bq, 1024, 0, stream>>>(part, labels, xbar, wa, wb, out);
}

// Round 7
// 241.189 us; speedup vs baseline: 1.7209x; 1.0471x over previous
//
#include <hip/hip_runtime.h>
#include <math.h>

#define Bq 8
#define T 512
#define D 1024
#define R 4
#define V 2048
#define NCOL (V * R * R)        // 32768 columns of w_vocab
#define DSPLIT 16
#define DCHUNK (D / DSPLIT)     // 64 d-rows per k_core block
#define CBLK 1024               // cols per k_core block (256 thr * float4)
#define NTC 32                  // t-chunks in k_xbar (16 t each)

// ---------------------------------------------------------------------------
// K1: partial[b][tc][d] = sum of 16 t's of x[b][.][d].  No atomics, no memset.
// grid (8, 32) x 256 threads, float4 coalesced loads+stores.
// Block (0,0) thread 0 zeroes the output scalar (replaces a memset).
// ---------------------------------------------------------------------------
__global__ void k_xbar(const float* __restrict__ x, float* __restrict__ partial,
                       float* __restrict__ out) {
    int b   = blockIdx.x;
    int tc  = blockIdx.y;          // 32 chunks of 16 timesteps
    int tid = threadIdx.x;         // 256 -> 1024 d via float4
    if (b == 0 && tc == 0 && tid == 0) out[0] = 0.f;
    const float4* xp = (const float4*)(x + ((size_t)b * T + (size_t)tc * 16) * D) + tid;
    float4 acc = make_float4(0.f, 0.f, 0.f, 0.f);
#pragma unroll
    for (int t = 0; t < 16; ++t) {
        float4 v = xp[t * (D / 4)];
        acc.x += v.x; acc.y += v.y; acc.z += v.z; acc.w += v.w;
    }
    *(float4*)(partial + ((size_t)b * NTC + tc) * D + tid * 4) = acc;
}

// ---------------------------------------------------------------------------
// K2: part[ds][b][col] = sum_{d in chunk ds} xbar[b][d] * w_vocab[d][col]
// grid (32, 16) x 256 threads. Prologue: (a) reduce partial -> xs in LDS,
// (b) build label-presence bitmask (8 x 2048 bits) in LDS from the 16 KB
// labels array (L2-hot). Stores of part are predicated on the mask: only
// ~22% of (b,col) entries are ever gathered -> part HBM writes 16 -> ~3.5 MiB.
// Main loop streams the full 128 MB of w_vocab exactly once (8 waves/CU,
// unroll 8 -> 8 KB/wave in flight).
// ---------------------------------------------------------------------------
__global__ void k_core(const float* __restrict__ wv, const float* __restrict__ partial,
                       const int* __restrict__ labels,
                       float* __restrict__ xbar, float* __restrict__ part) {
    __shared__ float xs[Bq * DCHUNK];      // 2 KB
    __shared__ unsigned int msk[Bq * 64];  // 8 b x 64 words = 2048 bits/b
    int tid  = threadIdx.x;            // 0..255
    int colb = blockIdx.x;             // 0..31
    int ds   = blockIdx.y;             // 0..15
    int d0   = ds * DCHUNK;

    // zero mask words (512 words, 2 per thread)
    msk[tid] = 0u; msk[tid + 256] = 0u;

    // reduce partial -> xs (512 values, 2 per thread)
#pragma unroll
    for (int h = 0; h < 2; ++h) {
        int q  = tid + h * 256;        // 0..511
        int b  = q >> 6;
        int dd = q & 63;
        const float* pp = partial + (size_t)b * NTC * D + d0 + dd;
        float s = 0.f;
#pragma unroll
        for (int tc = 0; tc < NTC; ++tc) s += pp[(size_t)tc * D];
        xs[q] = s;
    }
    __syncthreads();

    // build label-presence mask: 4096 labels, 16 per thread
#pragma unroll
    for (int h = 0; h < 16; ++h) {
        int idx = tid * 16 + h;        // 0..4095 = b*T + t
        int b   = idx >> 9;
        int y   = labels[idx];
        atomicOr(&msk[b * 64 + (y >> 5)], 1u << (y & 31));
    }

    if (colb == 0 && tid < 128) {      // write xbar slice back for the chain
        int q4 = tid * 4;
        int b  = q4 >> 6;
        int dd = q4 & 63;
        *(float4*)(xbar + b * D + d0 + dd) = *(const float4*)(xs + q4);
    }
    __syncthreads();

    int col = colb * CBLK + tid * 4;
    int y   = (colb * 256 + tid) & (V - 1);   // (col>>2) & (V-1)
    const float4* wp = (const float4*)(wv + (size_t)d0 * NCOL + col);
    float4 acc[Bq];
#pragma unroll
    for (int b = 0; b < Bq; ++b) acc[b] = make_float4(0.f, 0.f, 0.f, 0.f);

#pragma unroll 8
    for (int d = 0; d < DCHUNK; ++d) {
        float4 w = wp[(size_t)d * (NCOL / 4)];
#pragma unroll
        for (int b = 0; b < Bq; ++b) {
            float xv = xs[b * DCHUNK + d];
            acc[b].x += w.x * xv;
            acc[b].y += w.y * xv;
            acc[b].z += w.z * xv;
            acc[b].w += w.w * xv;
        }
    }

#pragma unroll
    for (int b = 0; b < Bq; ++b) {
        if ((msk[b * 64 + (y >> 5)] >> (y & 31)) & 1u)
            *(float4*)(part + ((size_t)ds * Bq + b) * NCOL + col) = acc[b];
    }
}

// ---------------------------------------------------------------------------
// K3: gather + column-normalize + per-block chunk product.
// grid (8 b, 8 tc) x 256 threads — 64 blocks keeps the scatter phase spread
// over 64 CUs (rounds 3/6 showed narrow grids lose ~8-20 us here).
// thread = (t_local, i): 16 independent float4 loads in flight; column sums
// via shfl_xor in the 4-lane group; matrices land in LDS; threads 0..7 then
// build the in-order product of this block's 64 matrices -> bprod[b][tc].
// ---------------------------------------------------------------------------
__global__ void k_gather(const float* __restrict__ part, const int* __restrict__ labels,
                         float* __restrict__ bprod) {
    __shared__ float Mn_s[64 * 16];   // 4 KB: this block's 64 matrices
    __shared__ float gm[8][17];       // chunk products, +1 pad
    int b   = blockIdx.x;
    int tc  = blockIdx.y;
    int tid = threadIdx.x;
    int tl  = tid >> 2;               // 0..63 local t
    int i   = tid & 3;                // matrix row
    int t   = tc * 64 + tl;
    int y   = labels[b * T + t];

    const float* pb = part + (size_t)b * NCOL + (size_t)i * (V * R) + (size_t)y * R;
    float4 g = make_float4(0.f, 0.f, 0.f, 0.f);
#pragma unroll
    for (int ds = 0; ds < DSPLIT; ++ds) {
        float4 v = *(const float4*)(pb + (size_t)ds * (Bq * NCOL));
        g.x += v.x; g.y += v.y; g.z += v.z; g.w += v.w;
    }
    g.x = fabsf(g.x); g.y = fabsf(g.y); g.z = fabsf(g.z); g.w = fabsf(g.w);

    float sx = g.x, sy = g.y, sz = g.z, sw = g.w;
    sx += __shfl_xor(sx, 1); sy += __shfl_xor(sy, 1);
    sz += __shfl_xor(sz, 1); sw += __shfl_xor(sw, 1);
    sx += __shfl_xor(sx, 2); sy += __shfl_xor(sy, 2);
    sz += __shfl_xor(sz, 2); sw += __shfl_xor(sw, 2);

    float4 o = make_float4(g.x / sx, g.y / sy, g.z / sz, g.w / sw);
    *(float4*)(Mn_s + tl * 16 + i * 4) = o;
    __syncthreads();

    // ---- chunk product Q_c = M_{c*8+7} ... M_{c*8} (threads 0..7) ----
    int c = tid;
    if (c < 8) {
        const float* mp = Mn_s + c * 8 * 16;
        float P[R][R];
        {
            float4 m0 = *(const float4*)(mp + 0);
            float4 m1 = *(const float4*)(mp + 4);
            float4 m2 = *(const float4*)(mp + 8);
            float4 m3 = *(const float4*)(mp + 12);
            P[0][0]=m0.x; P[0][1]=m0.y; P[0][2]=m0.z; P[0][3]=m0.w;
            P[1][0]=m1.x; P[1][1]=m1.y; P[1][2]=m1.z; P[1][3]=m1.w;
            P[2][0]=m2.x; P[2][1]=m2.y; P[2][2]=m2.z; P[2][3]=m2.w;
            P[3][0]=m3.x; P[3][1]=m3.y; P[3][2]=m3.z; P[3][3]=m3.w;
        }
#pragma unroll
        for (int k = 1; k < 8; ++k) {
            float4 m0 = *(const float4*)(mp + k * 16 + 0);
            float4 m1 = *(const float4*)(mp + k * 16 + 4);
            float4 m2 = *(const float4*)(mp + k * 16 + 8);
            float4 m3 = *(const float4*)(mp + k * 16 + 12);
            float M[R][R] = {{m0.x, m0.y, m0.z, m0.w},
                             {m1.x, m1.y, m1.z, m1.w},
                             {m2.x, m2.y, m2.z, m2.w},
                             {m3.x, m3.y, m3.z, m3.w}};
            float N[R][R];
#pragma unroll
            for (int ii = 0; ii < R; ++ii)
#pragma unroll
                for (int j = 0; j < R; ++j)
                    N[ii][j] = M[ii][0] * P[0][j] + M[ii][1] * P[1][j] +
                               M[ii][2] * P[2][j] + M[ii][3] * P[3][j];
#pragma unroll
            for (int ii = 0; ii < R; ++ii)
#pragma unroll
                for (int j = 0; j < R; ++j) P[ii][j] = N[ii][j];
        }
#pragma unroll
        for (int ii = 0; ii < R; ++ii)
#pragma unroll
            for (int j = 0; j < R; ++j) gm[c][ii * 4 + j] = P[ii][j];
    }
    __syncthreads();

    // ---- 3-level in-order tree: C_c <- C_{c+step} * C_c ----
    for (int rnd = 0; rnd < 3; ++rnd) {
        int step = 1 << rnd;
        bool act = (c < 8) && ((c & (2 * step - 1)) == 0);
        float N2[R][R];
        if (act) {
            float A[R][R], Bm[R][R];
#pragma unroll
            for (int ii = 0; ii < R; ++ii)
#pragma unroll
                for (int j = 0; j < R; ++j) {
                    A[ii][j]  = gm[c + step][ii * 4 + j];
                    Bm[ii][j] = gm[c][ii * 4 + j];
                }
#pragma unroll
            for (int ii = 0; ii < R; ++ii)
#pragma unroll
                for (int j = 0; j < R; ++j)
                    N2[ii][j] = A[ii][0] * Bm[0][j] + A[ii][1] * Bm[1][j] +
                                A[ii][2] * Bm[2][j] + A[ii][3] * Bm[3][j];
        }
        __syncthreads();
        if (act) {
#pragma unroll
            for (int ii = 0; ii < R; ++ii)
#pragma unroll
                for (int j = 0; j < R; ++j) gm[c][ii * 4 + j] = N2[ii][j];
        }
        __syncthreads();
    }

    if (tid < 4)   // write block product (4 float4s)
        *(float4*)(bprod + ((size_t)(b * 8 + tc)) * 16 + tid * 4) =
            *(const float4*)(&gm[0][tid * 4]);
}

// ---------------------------------------------------------------------------
// K4: one block per batch, 64 threads. alpha/beta seg dots; combine the 8
// block products in order (3-level tree); finalize loss.
// ---------------------------------------------------------------------------
__global__ void k_chain(const float* __restrict__ bprod, const float* __restrict__ xbar,
                        const float* __restrict__ wa, const float* __restrict__ wb,
                        float* __restrict__ out) {
    __shared__ float mats[8][17];     // +1 pad
    __shared__ float abp[64];
    int b   = blockIdx.x;
    int tid = threadIdx.x;            // 0..63

    // ---- alpha/beta partial dots (8 segs x {a,b} x 4 r) ----
    {
        int r   = tid & 3;
        int sel = (tid >> 2) & 1;
        int seg = tid >> 3;           // 0..7, 128 d each
        const float* w  = sel ? wb : wa;
        const float* xp = xbar + b * D;
        float s = 0.f;
#pragma unroll 8
        for (int d = seg * 128; d < seg * 128 + 128; ++d)
            s += xp[d] * w[d * R + r];
        abp[tid] = s;
    }

    // ---- load 8 block products (threads 0..31: one float4 each) ----
    if (tid < 32) {
        int c = tid >> 2, q = tid & 3;
        *(float4*)(&mats[c][q * 4]) =
            *(const float4*)(bprod + ((size_t)(b * 8 + c)) * 16 + q * 4);
    }
    __syncthreads();

    // ---- 3-level in-order tree: C_c <- C_{c+step} * C_c ----
    int c = tid;
    for (int rnd = 0; rnd < 3; ++rnd) {
        int step = 1 << rnd;
        bool act = (c < 8) && ((c & (2 * step - 1)) == 0);
        float N2[R][R];
        if (act) {
            float A[R][R], Bm[R][R];
#pragma unroll
            for (int i = 0; i < R; ++i)
#pragma unroll
                for (int j = 0; j < R; ++j) {
                    A[i][j]  = mats[c + step][i * 4 + j];
                    Bm[i][j] = mats[c][i * 4 + j];
                }
#pragma unroll
            for (int i = 0; i < R; ++i)
#pragma unroll
                for (int j = 0; j < R; ++j)
                    N2[i][j] = A[i][0] * Bm[0][j] + A[i][1] * Bm[1][j] +
                               A[i][2] * Bm[2][j] + A[i][3] * Bm[3][j];
        }
        __syncthreads();
        if (act) {
#pragma unroll
            for (int i = 0; i < R; ++i)
#pragma unroll
                for (int j = 0; j < R; ++j) mats[c][i * 4 + j] = N2[i][j];
        }
        __syncthreads();
    }

    // ---- finalize this batch ----
    if (tid == 0) {
        float a[R], be[R];
#pragma unroll
        for (int r = 0; r < R; ++r) {
            float sa = 0.f, sb = 0.f;
#pragma unroll
            for (int seg = 0; seg < 8; ++seg) {
                sa += abp[(seg << 3) | r];
                sb += abp[(seg << 3) | 4 | r];
            }
            a[r] = sa; be[r] = sb;
        }
        float sa = fabsf(a[0]) + fabsf(a[1]) + fabsf(a[2]) + fabsf(a[3]);
        float v0[R];
#pragma unroll
        for (int r = 0; r < R; ++r) v0[r] = fabsf(a[r]) / sa;
        float v[R];
#pragma unroll
        for (int i = 0; i < R; ++i)
            v[i] = mats[0][i * 4 + 0] * v0[0] + mats[0][i * 4 + 1] * v0[1] +
                   mats[0][i * 4 + 2] * v0[2] + mats[0][i * 4 + 3] * v0[3];
        float sb = fabsf(be[0]) + fabsf(be[1]) + fabsf(be[2]) + fabsf(be[3]);
        float prob = (fabsf(be[0]) * v[0] + fabsf(be[1]) * v[1] +
                      fabsf(be[2]) * v[2] + fabsf(be[3]) * v[3]) / sb;
        atomicAdd(out, -logf(prob) * 0.125f);
    }
}

extern "C" void kernel_launch(void* const* d_in, const int* in_sizes, int n_in,
                              void* d_out, int out_size, void* d_ws, size_t ws_size,
                              hipStream_t stream) {
    const float* x      = (const float*)d_in[0];   // [8,512,1024] fp32
    const int*   labels = (const int*)d_in[1];     // [8,512] int32
    const float* wa     = (const float*)d_in[2];   // [1024,4]
    const float* wb     = (const float*)d_in[3];   // [1024,4]
    const float* wv     = (const float*)d_in[4];   // [1024,32768]
    float* out = (float*)d_out;                    // scalar loss

    float* xbar    = (float*)d_ws;                           // 8192 floats
    float* partial = xbar + Bq * D;                          // 8*32*1024 = 1 MiB
    float* part    = partial + (size_t)Bq * NTC * D;         // 16*8*32768 = 16 MiB
    float* bprod   = part + (size_t)DSPLIT * Bq * NCOL;      // 8*8*16 floats

    k_xbar<<<dim3(Bq, NTC), 256, 0, stream>>>(x, partial, out);
    k_core<<<dim3(NCOL / CBLK, DSPLIT), 256, 0, stream>>>(wv, partial, labels, xbar, part);
    k_gather<<<dim3(Bq, 8), 256, 0, stream>>>(part, labels, bprod);
    k_chain<<<Bq, 64, 0, stream>>>(bprod, xbar, wa, wb, out);
}

// Round 8
// 230.912 us; speedup vs baseline: 1.7975x; 1.0445x over previous
//
#include <hip/hip_runtime.h>
#include <math.h>

#define Bq 8
#define T 512
#define D 1024
#define R 4
#define V 2048
#define NCOL (V * R * R)        // 32768 columns of w_vocab
#define DSPLIT 16
#define DCHUNK (D / DSPLIT)     // 64 d-rows per k_core block
#define CBLK 1024               // cols per k_core block (256 thr * float4)
#define NTC 32                  // t-chunks in k_xbar (16 t each)

// ---------------------------------------------------------------------------
// K1: partial[b][tc][d] = sum of 16 t's of x[b][.][d].  No atomics, no memset.
// grid (8, 32) x 256 threads, float4 coalesced loads+stores.
// Block (0,0) thread 0 zeroes the output scalar (replaces a memset).
// ---------------------------------------------------------------------------
__global__ void k_xbar(const float* __restrict__ x, float* __restrict__ partial,
                       float* __restrict__ out) {
    int b   = blockIdx.x;
    int tc  = blockIdx.y;          // 32 chunks of 16 timesteps
    int tid = threadIdx.x;         // 256 -> 1024 d via float4
    if (b == 0 && tc == 0 && tid == 0) out[0] = 0.f;
    const float4* xp = (const float4*)(x + ((size_t)b * T + (size_t)tc * 16) * D) + tid;
    float4 acc = make_float4(0.f, 0.f, 0.f, 0.f);
#pragma unroll
    for (int t = 0; t < 16; ++t) {
        float4 v = xp[t * (D / 4)];
        acc.x += v.x; acc.y += v.y; acc.z += v.z; acc.w += v.w;
    }
    *(float4*)(partial + ((size_t)b * NTC + tc) * D + tid * 4) = acc;
}

// ---------------------------------------------------------------------------
// K2: part[ds][b][col] = sum_{d in chunk ds} xbar[b][d] * w_vocab[d][col]
// grid (32, 16) x 256 threads. Prologue reduces partial[b][tc][d-slice] ->
// xs in LDS (L2-resident reads, shared by 32 colb-blocks).
// colb==0 blocks also write xbar back to global for the chain's alpha/beta.
// Main loop streams the full 128 MB of w_vocab exactly once (8 waves/CU,
// unroll 8 -> 8 KB/wave in flight). Stores stay DENSE: round-7 showed
// predicated ~22%-density stores cost MORE (partial-cacheline RMW).
// ---------------------------------------------------------------------------
__global__ void k_core(const float* __restrict__ wv, const float* __restrict__ partial,
                       float* __restrict__ xbar, float* __restrict__ part) {
    __shared__ float xs[Bq * DCHUNK];  // 8 x 64 floats = 2 KB
    int tid  = threadIdx.x;            // 0..255
    int colb = blockIdx.x;             // 0..31
    int ds   = blockIdx.y;             // 0..15
    int d0   = ds * DCHUNK;

    // reduce partial -> xs (512 values, 2 per thread)
#pragma unroll
    for (int h = 0; h < 2; ++h) {
        int q  = tid + h * 256;        // 0..511
        int b  = q >> 6;
        int dd = q & 63;
        const float* pp = partial + (size_t)b * NTC * D + d0 + dd;
        float s = 0.f;
#pragma unroll
        for (int tc = 0; tc < NTC; ++tc) s += pp[(size_t)tc * D];
        xs[q] = s;
    }
    __syncthreads();

    if (colb == 0 && tid < 128) {      // write xbar slice back for the chain
        int q4 = tid * 4;
        int b  = q4 >> 6;
        int dd = q4 & 63;
        *(float4*)(xbar + b * D + d0 + dd) = *(const float4*)(xs + q4);
    }

    int col = colb * CBLK + tid * 4;
    const float4* wp = (const float4*)(wv + (size_t)d0 * NCOL + col);
    float4 acc[Bq];
#pragma unroll
    for (int b = 0; b < Bq; ++b) acc[b] = make_float4(0.f, 0.f, 0.f, 0.f);

#pragma unroll 8
    for (int d = 0; d < DCHUNK; ++d) {
        float4 w = wp[(size_t)d * (NCOL / 4)];
#pragma unroll
        for (int b = 0; b < Bq; ++b) {
            float xv = xs[b * DCHUNK + d];
            acc[b].x += w.x * xv;
            acc[b].y += w.y * xv;
            acc[b].z += w.z * xv;
            acc[b].w += w.w * xv;
        }
    }

#pragma unroll
    for (int b = 0; b < Bq; ++b)
        *(float4*)(part + ((size_t)ds * Bq + b) * NCOL + col) = acc[b];
}

// ---------------------------------------------------------------------------
// K3: gather + column-normalize + per-block chunk product.
// grid (8 b, 8 tc) x 256 threads — 64 blocks keeps the scatter phase spread
// over 64 CUs (rounds 3/6: narrow grids lose 8-20 us here).
// thread = (t_local, i): 16 independent float4 loads in flight; column sums
// via shfl_xor in the 4-lane group; matrices land in LDS; threads 0..7 then
// build the in-order product of this block's 64 matrices -> bprod[b][tc].
// Removes the Mn global round-trip + most chain work (round-7 change (b)).
// ---------------------------------------------------------------------------
__global__ void k_gather(const float* __restrict__ part, const int* __restrict__ labels,
                         float* __restrict__ bprod) {
    __shared__ float Mn_s[64 * 16];   // 4 KB: this block's 64 matrices
    __shared__ float gm[8][17];       // chunk products, +1 pad
    int b   = blockIdx.x;
    int tc  = blockIdx.y;
    int tid = threadIdx.x;
    int tl  = tid >> 2;               // 0..63 local t
    int i   = tid & 3;                // matrix row
    int t   = tc * 64 + tl;
    int y   = labels[b * T + t];

    const float* pb = part + (size_t)b * NCOL + (size_t)i * (V * R) + (size_t)y * R;
    float4 g = make_float4(0.f, 0.f, 0.f, 0.f);
#pragma unroll
    for (int ds = 0; ds < DSPLIT; ++ds) {
        float4 v = *(const float4*)(pb + (size_t)ds * (Bq * NCOL));
        g.x += v.x; g.y += v.y; g.z += v.z; g.w += v.w;
    }
    g.x = fabsf(g.x); g.y = fabsf(g.y); g.z = fabsf(g.z); g.w = fabsf(g.w);

    float sx = g.x, sy = g.y, sz = g.z, sw = g.w;
    sx += __shfl_xor(sx, 1); sy += __shfl_xor(sy, 1);
    sz += __shfl_xor(sz, 1); sw += __shfl_xor(sw, 1);
    sx += __shfl_xor(sx, 2); sy += __shfl_xor(sy, 2);
    sz += __shfl_xor(sz, 2); sw += __shfl_xor(sw, 2);

    float4 o = make_float4(g.x / sx, g.y / sy, g.z / sz, g.w / sw);
    *(float4*)(Mn_s + tl * 16 + i * 4) = o;
    __syncthreads();

    // ---- chunk product Q_c = M_{c*8+7} ... M_{c*8} (threads 0..7) ----
    int c = tid;
    if (c < 8) {
        const float* mp = Mn_s + c * 8 * 16;
        float P[R][R];
        {
            float4 m0 = *(const float4*)(mp + 0);
            float4 m1 = *(const float4*)(mp + 4);
            float4 m2 = *(const float4*)(mp + 8);
            float4 m3 = *(const float4*)(mp + 12);
            P[0][0]=m0.x; P[0][1]=m0.y; P[0][2]=m0.z; P[0][3]=m0.w;
            P[1][0]=m1.x; P[1][1]=m1.y; P[1][2]=m1.z; P[1][3]=m1.w;
            P[2][0]=m2.x; P[2][1]=m2.y; P[2][2]=m2.z; P[2][3]=m2.w;
            P[3][0]=m3.x; P[3][1]=m3.y; P[3][2]=m3.z; P[3][3]=m3.w;
        }
#pragma unroll
        for (int k = 1; k < 8; ++k) {
            float4 m0 = *(const float4*)(mp + k * 16 + 0);
            float4 m1 = *(const float4*)(mp + k * 16 + 4);
            float4 m2 = *(const float4*)(mp + k * 16 + 8);
            float4 m3 = *(const float4*)(mp + k * 16 + 12);
            float M[R][R] = {{m0.x, m0.y, m0.z, m0.w},
                             {m1.x, m1.y, m1.z, m1.w},
                             {m2.x, m2.y, m2.z, m2.w},
                             {m3.x, m3.y, m3.z, m3.w}};
            float N[R][R];
#pragma unroll
            for (int ii = 0; ii < R; ++ii)
#pragma unroll
                for (int j = 0; j < R; ++j)
                    N[ii][j] = M[ii][0] * P[0][j] + M[ii][1] * P[1][j] +
                               M[ii][2] * P[2][j] + M[ii][3] * P[3][j];
#pragma unroll
            for (int ii = 0; ii < R; ++ii)
#pragma unroll
                for (int j = 0; j < R; ++j) P[ii][j] = N[ii][j];
        }
#pragma unroll
        for (int ii = 0; ii < R; ++ii)
#pragma unroll
            for (int j = 0; j < R; ++j) gm[c][ii * 4 + j] = P[ii][j];
    }
    __syncthreads();

    // ---- 3-level in-order tree: C_c <- C_{c+step} * C_c ----
    for (int rnd = 0; rnd < 3; ++rnd) {
        int step = 1 << rnd;
        bool act = (c < 8) && ((c & (2 * step - 1)) == 0);
        float N2[R][R];
        if (act) {
            float A[R][R], Bm[R][R];
#pragma unroll
            for (int ii = 0; ii < R; ++ii)
#pragma unroll
                for (int j = 0; j < R; ++j) {
                    A[ii][j]  = gm[c + step][ii * 4 + j];
                    Bm[ii][j] = gm[c][ii * 4 + j];
                }
#pragma unroll
            for (int ii = 0; ii < R; ++ii)
#pragma unroll
                for (int j = 0; j < R; ++j)
                    N2[ii][j] = A[ii][0] * Bm[0][j] + A[ii][1] * Bm[1][j] +
                                A[ii][2] * Bm[2][j] + A[ii][3] * Bm[3][j];
        }
        __syncthreads();
        if (act) {
#pragma unroll
            for (int ii = 0; ii < R; ++ii)
#pragma unroll
                for (int j = 0; j < R; ++j) gm[c][ii * 4 + j] = N2[ii][j];
        }
        __syncthreads();
    }

    if (tid < 4)   // write block product (4 float4s)
        *(float4*)(bprod + ((size_t)(b * 8 + tc)) * 16 + tid * 4) =
            *(const float4*)(&gm[0][tid * 4]);
}

// ---------------------------------------------------------------------------
// K4: one block per batch, 64 threads. alpha/beta seg dots; combine the 8
// block products in order (3-level tree); finalize loss.
// ---------------------------------------------------------------------------
__global__ void k_chain(const float* __restrict__ bprod, const float* __restrict__ xbar,
                        const float* __restrict__ wa, const float* __restrict__ wb,
                        float* __restrict__ out) {
    __shared__ float mats[8][17];     // +1 pad
    __shared__ float abp[64];
    int b   = blockIdx.x;
    int tid = threadIdx.x;            // 0..63

    // ---- alpha/beta partial dots (8 segs x {a,b} x 4 r) ----
    {
        int r   = tid & 3;
        int sel = (tid >> 2) & 1;
        int seg = tid >> 3;           // 0..7, 128 d each
        const float* w  = sel ? wb : wa;
        const float* xp = xbar + b * D;
        float s = 0.f;
#pragma unroll 8
        for (int d = seg * 128; d < seg * 128 + 128; ++d)
            s += xp[d] * w[d * R + r];
        abp[tid] = s;
    }

    // ---- load 8 block products (threads 0..31: one float4 each) ----
    if (tid < 32) {
        int c = tid >> 2, q = tid & 3;
        *(float4*)(&mats[c][q * 4]) =
            *(const float4*)(bprod + ((size_t)(b * 8 + c)) * 16 + q * 4);
    }
    __syncthreads();

    // ---- 3-level in-order tree: C_c <- C_{c+step} * C_c ----
    int c = tid;
    for (int rnd = 0; rnd < 3; ++rnd) {
        int step = 1 << rnd;
        bool act = (c < 8) && ((c & (2 * step - 1)) == 0);
        float N2[R][R];
        if (act) {
            float A[R][R], Bm[R][R];
#pragma unroll
            for (int i = 0; i < R; ++i)
#pragma unroll
                for (int j = 0; j < R; ++j) {
                    A[i][j]  = mats[c + step][i * 4 + j];
                    Bm[i][j] = mats[c][i * 4 + j];
                }
#pragma unroll
            for (int i = 0; i < R; ++i)
#pragma unroll
                for (int j = 0; j < R; ++j)
                    N2[i][j] = A[i][0] * Bm[0][j] + A[i][1] * Bm[1][j] +
                               A[i][2] * Bm[2][j] + A[i][3] * Bm[3][j];
        }
        __syncthreads();
        if (act) {
#pragma unroll
            for (int i = 0; i < R; ++i)
#pragma unroll
                for (int j = 0; j < R; ++j) mats[c][i * 4 + j] = N2[i][j];
        }
        __syncthreads();
    }

    // ---- finalize this batch ----
    if (tid == 0) {
        float a[R], be[R];
#pragma unroll
        for (int r = 0; r < R; ++r) {
            float sa = 0.f, sb = 0.f;
#pragma unroll
            for (int seg = 0; seg < 8; ++seg) {
                sa += abp[(seg << 3) | r];
                sb += abp[(seg << 3) | 4 | r];
            }
            a[r] = sa; be[r] = sb;
        }
        float sa = fabsf(a[0]) + fabsf(a[1]) + fabsf(a[2]) + fabsf(a[3]);
        float v0[R];
#pragma unroll
        for (int r = 0; r < R; ++r) v0[r] = fabsf(a[r]) / sa;
        float v[R];
#pragma unroll
        for (int i = 0; i < R; ++i)
            v[i] = mats[0][i * 4 + 0] * v0[0] + mats[0][i * 4 + 1] * v0[1] +
                   mats[0][i * 4 + 2] * v0[2] + mats[0][i * 4 + 3] * v0[3];
        float sb = fabsf(be[0]) + fabsf(be[1]) + fabsf(be[2]) + fabsf(be[3]);
        float prob = (fabsf(be[0]) * v[0] + fabsf(be[1]) * v[1] +
                      fabsf(be[2]) * v[2] + fabsf(be[3]) * v[3]) / sb;
        atomicAdd(out, -logf(prob) * 0.125f);
    }
}

extern "C" void kernel_launch(void* const* d_in, const int* in_sizes, int n_in,
                              void* d_out, int out_size, void* d_ws, size_t ws_size,
                              hipStream_t stream) {
    const float* x      = (const float*)d_in[0];   // [8,512,1024] fp32
    const int*   labels = (const int*)d_in[1];     // [8,512] int32
    const float* wa     = (const float*)d_in[2];   // [1024,4]
    const float* wb     = (const float*)d_in[3];   // [1024,4]
    const float* wv     = (const float*)d_in[4];   // [1024,32768]
    float* out = (float*)d_out;                    // scalar loss

    float* xbar    = (float*)d_ws;                           // 8192 floats
    float* partial = xbar + Bq * D;                          // 8*32*1024 = 1 MiB
    float* part    = partial + (size_t)Bq * NTC * D;         // 16*8*32768 = 16 MiB
    float* bprod   = part + (size_t)DSPLIT * Bq * NCOL;      // 8*8*16 floats

    k_xbar<<<dim3(Bq, NTC), 256, 0, stream>>>(x, partial, out);
    k_core<<<dim3(NCOL / CBLK, DSPLIT), 256, 0, stream>>>(wv, partial, xbar, part);
    k_gather<<<dim3(Bq, 8), 256, 0, stream>>>(part, labels, bprod);
    k_chain<<<Bq, 64, 0, stream>>>(bprod, xbar, wa, wb, out);
}